// Round 3
// baseline (487.703 us; speedup 1.0000x reference)
//
#include <hip/hip_runtime.h>

#define Bn 4
#define Sn 1024
#define En 1024
#define Wn 768
#define Hn 12
#define Dn 64

typedef __attribute__((ext_vector_type(8))) short short8;
typedef __attribute__((ext_vector_type(4))) short short4v;
typedef __attribute__((ext_vector_type(4))) float floatx4;

#define MFMA16(A, B, C) __builtin_amdgcn_mfma_f32_16x16x32_bf16(A, B, C, 0, 0, 0)

__device__ __forceinline__ unsigned short f2bf_rn(float f) {
    unsigned int u = __float_as_uint(f);
    unsigned int r = u + 0x7fffu + ((u >> 16) & 1u);
    return (unsigned short)(r >> 16);
}
__device__ __forceinline__ float bf2f(unsigned short h) {
    return __uint_as_float(((unsigned int)h) << 16);
}

__device__ __forceinline__ void gload_lds16(const unsigned short* g, unsigned short* l) {
    __builtin_amdgcn_global_load_lds(
        (const __attribute__((address_space(1))) void*)g,
        (__attribute__((address_space(3))) void*)l, 16, 0, 0);
}

// ---------------------------------------------------------------------------
// Split fp32 -> bf16 hi/lo.  x: [4096][1024] -> xh/xl [4096][768]
// ---------------------------------------------------------------------------
__global__ __launch_bounds__(256) void split_x_kernel(
    const float* __restrict__ x, unsigned short* __restrict__ xh,
    unsigned short* __restrict__ xl)
{
    int e = (blockIdx.x * 256 + threadIdx.x) * 4;   // over 4096*768
    int row = e / Wn, col = e - row * Wn;
    float4 v = *(const float4*)(x + (size_t)row * En + col);
    float f[4] = {v.x, v.y, v.z, v.w};
    short4v h, l;
    #pragma unroll
    for (int i = 0; i < 4; ++i) {
        unsigned short hh = f2bf_rn(f[i]);
        h[i] = (short)hh;
        l[i] = (short)f2bf_rn(f[i] - bf2f(hh));
    }
    *(short4v*)(xh + e) = h;
    *(short4v*)(xl + e) = l;
}

// w: [1024][1024], slice [768][768] -> dh/dl (768 cols)
__global__ __launch_bounds__(256) void split_w_kernel(
    const float* __restrict__ w, unsigned short* __restrict__ dh,
    unsigned short* __restrict__ dl)
{
    int e = (blockIdx.x * 256 + threadIdx.x) * 4;   // over 768*768
    int row = e / Wn, col = e - row * Wn;
    float4 v = *(const float4*)(w + (size_t)row * En + col);
    float f[4] = {v.x, v.y, v.z, v.w};
    short4v h, l;
    #pragma unroll
    for (int i = 0; i < 4; ++i) {
        unsigned short hh = f2bf_rn(f[i]);
        h[i] = (short)hh;
        l[i] = (short)f2bf_rn(f[i] - bf2f(hh));
    }
    *(short4v*)(dh + e) = h;
    *(short4v*)(dl + e) = l;
}

__global__ __launch_bounds__(256) void concat_bias_kernel(
    const float* __restrict__ qb, const float* __restrict__ kb,
    const float* __restrict__ vb, float* __restrict__ bq)
{
    int t = blockIdx.x * 256 + threadIdx.x;
    if (t < Wn) bq[t] = qb[t];
    else if (t < 2 * Wn) bq[t] = kb[t - Wn];
    else if (t < 3 * Wn) bq[t] = vb[t - 2 * Wn];
}

// ---------------------------------------------------------------------------
// QKV GEMM: C[4096, 2304] = X @ Wqkv^T + b  via bf16x3 MFMA.  (unchanged)
// ---------------------------------------------------------------------------
__global__ __launch_bounds__(256) void qkv_mfma_kernel(
    const unsigned short* __restrict__ xh, const unsigned short* __restrict__ xl,
    const unsigned short* __restrict__ wh, const unsigned short* __restrict__ wl,
    const float* __restrict__ bq,
    unsigned short* __restrict__ qh_o, unsigned short* __restrict__ ql_o,
    unsigned short* __restrict__ kh_o, unsigned short* __restrict__ kl_o,
    unsigned short* __restrict__ vt_o)
{
    __shared__ __align__(16) unsigned short Ah[128 * 32];
    __shared__ __align__(16) unsigned short Al[128 * 32];
    __shared__ __align__(16) unsigned short Bh[128 * 32];
    __shared__ __align__(16) unsigned short Bl[128 * 32];

    const int tid = threadIdx.x;
    const int wave = tid >> 6, lane = tid & 63;
    const int quad = lane >> 4, l16 = lane & 15;
    const int m0 = blockIdx.x * 128, n0 = blockIdx.y * 128;
    const int wm = wave >> 1, wn = wave & 1;

    floatx4 acc[4][4] = {};

    const unsigned short* gsrc = (wave == 0) ? xh : (wave == 1) ? xl
                               : (wave == 2) ? wh : wl;
    unsigned short* ldst = (wave == 0) ? Ah : (wave == 1) ? Al
                         : (wave == 2) ? Bh : Bl;
    const int base_row = (wave < 2) ? m0 : n0;
    const int r_in = lane >> 2;                   // 0..15
    const int cs = (lane & 3) ^ (r_in & 3);       // swizzled global chunk

    for (int k0 = 0; k0 < Wn; k0 += 32) {
        #pragma unroll
        for (int i = 0; i < 8; ++i) {
            int r = i * 16 + r_in;
            const unsigned short* gp =
                gsrc + (size_t)(base_row + r) * Wn + k0 + cs * 8;
            gload_lds16(gp, ldst + i * 512);
        }
        __syncthreads();

        short8 afh[4], afl[4], bfh[4], bfl[4];
        #pragma unroll
        for (int t = 0; t < 4; ++t) {
            int mr = wm * 64 + t * 16 + l16;
            int ca = quad ^ (mr & 3);
            afh[t] = *(const short8*)(Ah + mr * 32 + ca * 8);
            afl[t] = *(const short8*)(Al + mr * 32 + ca * 8);
            int nr = wn * 64 + t * 16 + l16;
            int cb = quad ^ (nr & 3);
            bfh[t] = *(const short8*)(Bh + nr * 32 + cb * 8);
            bfl[t] = *(const short8*)(Bl + nr * 32 + cb * 8);
        }
        #pragma unroll
        for (int mt = 0; mt < 4; ++mt)
            #pragma unroll
            for (int nt = 0; nt < 4; ++nt) {
                acc[mt][nt] = MFMA16(afh[mt], bfh[nt], acc[mt][nt]);
                acc[mt][nt] = MFMA16(afh[mt], bfl[nt], acc[mt][nt]);
                acc[mt][nt] = MFMA16(afl[mt], bfh[nt], acc[mt][nt]);
            }
        __syncthreads();
    }

    const int which = n0 / Wn;                 // 0=q 1=k 2=v
    const int b = m0 >> 10;
    #pragma unroll
    for (int nt = 0; nt < 4; ++nt) {
        const int ng = n0 + wn * 64 + nt * 16 + l16;
        const float bias = bq[ng];
        const int f = ng - which * Wn;
        const int h = f >> 6, d = f & 63;
        #pragma unroll
        for (int mt = 0; mt < 4; ++mt) {
            const int mbase = m0 + wm * 64 + mt * 16 + quad * 4;
            const int s0 = mbase & (Sn - 1);
            if (which < 2) {
                unsigned short* oh = which ? kh_o : qh_o;
                unsigned short* ol = which ? kl_o : ql_o;
                size_t idx = (((size_t)(b * Hn + h)) * Sn + s0) * Dn + d;
                #pragma unroll
                for (int r = 0; r < 4; ++r) {
                    float vv = acc[mt][nt][r] + bias;
                    unsigned short hh = f2bf_rn(vv);
                    oh[idx + (size_t)r * Dn] = hh;
                    ol[idx + (size_t)r * Dn] = f2bf_rn(vv - bf2f(hh));
                }
            } else {
                size_t idx = (((size_t)(b * Hn + h)) * Dn + d) * Sn + s0;
                short4v pk;
                #pragma unroll
                for (int r = 0; r < 4; ++r)
                    pk[r] = (short)f2bf_rn(acc[mt][nt][r] + bias);
                *(short4v*)(vt_o + idx) = pk;
            }
        }
    }
}

// ---------------------------------------------------------------------------
// Attention: block = 32 q-rows x (h, b); 128 threads = 2 waves x 16 rows.
// 1536 blocks (~6/CU) for latency hiding.  XOR-swizzled LDS (stride 64,
// chunk ^= row&7) keeps b128 reads conflict-free with zero padding:
// LDS = 3*8KB (Kh,Kl,Vs) + 4KB Ps + msk = 28.3KB -> 5 blocks/CU.
// ---------------------------------------------------------------------------
__global__ __launch_bounds__(128) void attn_mfma_kernel(
    const unsigned short* __restrict__ qh, const unsigned short* __restrict__ ql,
    const unsigned short* __restrict__ kh, const unsigned short* __restrict__ kl,
    const unsigned short* __restrict__ vt, const int* __restrict__ mask,
    float* __restrict__ attn, unsigned short* __restrict__ aoh,
    unsigned short* __restrict__ aol)
{
    __shared__ __align__(16) unsigned short Kh[64 * 64];
    __shared__ __align__(16) unsigned short Kl[64 * 64];
    __shared__ __align__(16) unsigned short Vs[64 * 64];
    __shared__ __align__(16) unsigned short Ps[2][16 * 64];
    __shared__ float msk[64];

    const int tid = threadIdx.x;
    const int wave = tid >> 6, lane = tid & 63;
    const int quad = lane >> 4, l16 = lane & 15;
    const int qt = blockIdx.x, h = blockIdx.y, b = blockIdx.z;
    const int bh = b * Hn + h;
    const size_t kvbase = (size_t)bh * Sn * Dn;

    // Q fragments (A-operand: m=l16, k=quad*8+j)
    short8 qfh[2], qfl[2];
    {
        const int s = qt * 32 + wave * 16 + l16;
        const size_t off = kvbase + (size_t)s * Dn + quad * 8;
        qfh[0] = *(const short8*)(qh + off);
        qfh[1] = *(const short8*)(qh + off + 32);
        qfl[0] = *(const short8*)(ql + off);
        qfl[1] = *(const short8*)(ql + off + 32);
    }

    const int sr = tid >> 1;        // staging row 0..63
    const int sh = tid & 1;         // staging half (4 chunks of 8)
    const int swz = sr & 7;

    float lsum[4] = {0.f, 0.f, 0.f, 0.f};

    // ---- pass A: denominators ----
    for (int kt = 0; kt < 16; ++kt) {
        __syncthreads();
        {
            const size_t g = kvbase + (size_t)(kt * 64 + sr) * Dn + sh * 32;
            #pragma unroll
            for (int u = 0; u < 4; ++u) {
                int pc = (sh * 4 + u) ^ swz;
                *(short8*)&Kh[sr * 64 + pc * 8] = *(const short8*)(kh + g + u * 8);
                *(short8*)&Kl[sr * 64 + pc * 8] = *(const short8*)(kl + g + u * 8);
            }
            if (tid < 64) msk[tid] = (float)mask[b * Sn + kt * 64 + tid];
        }
        __syncthreads();
        #pragma unroll
        for (int ct = 0; ct < 4; ++ct) {
            floatx4 acc = {0.f, 0.f, 0.f, 0.f};
            const int key = ct * 16 + l16;
            #pragma unroll
            for (int ks = 0; ks < 2; ++ks) {
                const int pc = ((ks * 4 + quad) ^ (l16 & 7)) * 8;
                short8 b8h = *(const short8*)&Kh[key * 64 + pc];
                short8 b8l = *(const short8*)&Kl[key * 64 + pc];
                acc = MFMA16(qfh[ks], b8h, acc);
                acc = MFMA16(qfh[ks], b8l, acc);
                acc = MFMA16(qfl[ks], b8h, acc);
            }
            const float mv = msk[key];
            #pragma unroll
            for (int r = 0; r < 4; ++r)
                lsum[r] += __expf(acc[r] * 0.125f) * mv;
        }
    }

    // reduce across the 16 lanes of each quad row-group; invert
    #pragma unroll
    for (int r = 0; r < 4; ++r) {
        float v = lsum[r];
        v += __shfl_xor(v, 1, 64);
        v += __shfl_xor(v, 2, 64);
        v += __shfl_xor(v, 4, 64);
        v += __shfl_xor(v, 8, 64);
        lsum[r] = (v > 0.f) ? 1.f / v : 0.f;
    }

    floatx4 oacc[4] = {};
    const size_t vbase = (size_t)bh * Dn * Sn;

    // ---- pass B: weights out + PV ----
    for (int kt = 0; kt < 16; ++kt) {
        __syncthreads();
        {
            const size_t g = kvbase + (size_t)(kt * 64 + sr) * Dn + sh * 32;
            const size_t g2 = vbase + (size_t)sr * Sn + kt * 64 + sh * 32;
            #pragma unroll
            for (int u = 0; u < 4; ++u) {
                int pc = (sh * 4 + u) ^ swz;
                *(short8*)&Kh[sr * 64 + pc * 8] = *(const short8*)(kh + g + u * 8);
                *(short8*)&Kl[sr * 64 + pc * 8] = *(const short8*)(kl + g + u * 8);
                *(short8*)&Vs[sr * 64 + pc * 8] = *(const short8*)(vt + g2 + u * 8);
            }
            if (tid < 64) msk[tid] = (float)mask[b * Sn + kt * 64 + tid];
        }
        __syncthreads();

        #pragma unroll
        for (int ct = 0; ct < 4; ++ct) {
            floatx4 acc = {0.f, 0.f, 0.f, 0.f};
            const int key = ct * 16 + l16;
            #pragma unroll
            for (int ks = 0; ks < 2; ++ks) {
                const int pc = ((ks * 4 + quad) ^ (l16 & 7)) * 8;
                short8 b8h = *(const short8*)&Kh[key * 64 + pc];
                short8 b8l = *(const short8*)&Kl[key * 64 + pc];
                acc = MFMA16(qfh[ks], b8h, acc);
                acc = MFMA16(qfh[ks], b8l, acc);
                acc = MFMA16(qfl[ks], b8h, acc);
            }
            const float mv = msk[key];
            const int row0 = qt * 32 + wave * 16 + quad * 4;
            const int key_g = kt * 64 + key;
            const int pchunk = (key >> 3);
            #pragma unroll
            for (int r = 0; r < 4; ++r) {
                float p = __expf(acc[r] * 0.125f) * mv * lsum[r];
                attn[((size_t)bh * Sn + row0 + r) * Sn + key_g] = p;
                const int prow = quad * 4 + r;
                Ps[wave][prow * 64 + ((pchunk ^ (prow & 7)) * 8) + (key & 7)] = f2bf_rn(p);
            }
        }
        // PV: wave-local Ps (in-wave LDS ordering; compiler waits lgkmcnt)
        #pragma unroll
        for (int ks = 0; ks < 2; ++ks) {
            const int pc = ((ks * 4 + quad) ^ (l16 & 7)) * 8;
            short8 pf = *(const short8*)&Ps[wave][l16 * 64 + pc];
            #pragma unroll
            for (int dt = 0; dt < 4; ++dt) {
                const int d = dt * 16 + l16;
                short8 vf = *(const short8*)&Vs[d * 64 + pc];
                oacc[dt] = MFMA16(pf, vf, oacc[dt]);
            }
        }
    }

    // epilogue: ao -> bf16 hi/lo [B,S,W]
    const int s0 = qt * 32 + wave * 16 + quad * 4;
    #pragma unroll
    for (int dt = 0; dt < 4; ++dt)
        #pragma unroll
        for (int r = 0; r < 4; ++r) {
            float v = oacc[dt][r];
            size_t idx = ((size_t)(b * Sn + s0 + r)) * Wn + h * Dn + dt * 16 + l16;
            unsigned short hh = f2bf_rn(v);
            aoh[idx] = hh;
            aol[idx] = f2bf_rn(v - bf2f(hh));
        }
}

// ---------------------------------------------------------------------------
// O projection: out[4096,768] = AO @ Wo^T + b, bf16x3 MFMA, fp32 out. (unchanged)
// ---------------------------------------------------------------------------
__global__ __launch_bounds__(256) void oproj_mfma_kernel(
    const unsigned short* __restrict__ aoh, const unsigned short* __restrict__ aol,
    const unsigned short* __restrict__ wh, const unsigned short* __restrict__ wl,
    const float* __restrict__ ob, float* __restrict__ out)
{
    __shared__ __align__(16) unsigned short Ah[128 * 32];
    __shared__ __align__(16) unsigned short Al[128 * 32];
    __shared__ __align__(16) unsigned short Bh[128 * 32];
    __shared__ __align__(16) unsigned short Bl[128 * 32];

    const int tid = threadIdx.x;
    const int wave = tid >> 6, lane = tid & 63;
    const int quad = lane >> 4, l16 = lane & 15;
    const int m0 = blockIdx.x * 128, n0 = blockIdx.y * 128;
    const int wm = wave >> 1, wn = wave & 1;

    floatx4 acc[4][4] = {};

    const unsigned short* gsrc = (wave == 0) ? aoh : (wave == 1) ? aol
                               : (wave == 2) ? wh : wl;
    unsigned short* ldst = (wave == 0) ? Ah : (wave == 1) ? Al
                         : (wave == 2) ? Bh : Bl;
    const int base_row = (wave < 2) ? m0 : n0;
    const int r_in = lane >> 2;
    const int cs = (lane & 3) ^ (r_in & 3);

    for (int k0 = 0; k0 < Wn; k0 += 32) {
        #pragma unroll
        for (int i = 0; i < 8; ++i) {
            int r = i * 16 + r_in;
            const unsigned short* gp =
                gsrc + (size_t)(base_row + r) * Wn + k0 + cs * 8;
            gload_lds16(gp, ldst + i * 512);
        }
        __syncthreads();

        short8 afh[4], afl[4], bfh[4], bfl[4];
        #pragma unroll
        for (int t = 0; t < 4; ++t) {
            int mr = wm * 64 + t * 16 + l16;
            int ca = quad ^ (mr & 3);
            afh[t] = *(const short8*)(Ah + mr * 32 + ca * 8);
            afl[t] = *(const short8*)(Al + mr * 32 + ca * 8);
            int nr = wn * 64 + t * 16 + l16;
            int cb = quad ^ (nr & 3);
            bfh[t] = *(const short8*)(Bh + nr * 32 + cb * 8);
            bfl[t] = *(const short8*)(Bl + nr * 32 + cb * 8);
        }
        #pragma unroll
        for (int mt = 0; mt < 4; ++mt)
            #pragma unroll
            for (int nt = 0; nt < 4; ++nt) {
                acc[mt][nt] = MFMA16(afh[mt], bfh[nt], acc[mt][nt]);
                acc[mt][nt] = MFMA16(afh[mt], bfl[nt], acc[mt][nt]);
                acc[mt][nt] = MFMA16(afl[mt], bfh[nt], acc[mt][nt]);
            }
        __syncthreads();
    }

    #pragma unroll
    for (int nt = 0; nt < 4; ++nt) {
        const int ng = n0 + wn * 64 + nt * 16 + l16;
        const float bias = ob[ng];
        #pragma unroll
        for (int mt = 0; mt < 4; ++mt) {
            const int m = m0 + wm * 64 + mt * 16 + quad * 4;
            #pragma unroll
            for (int r = 0; r < 4; ++r)
                out[(size_t)(m + r) * Wn + ng] = acc[mt][nt][r] + bias;
        }
    }
}

// ---------------------------------------------------------------------------
extern "C" void kernel_launch(void* const* d_in, const int* in_sizes, int n_in,
                              void* d_out, int out_size, void* d_ws, size_t ws_size,
                              hipStream_t stream) {
    const float* x    = (const float*)d_in[0];
    const int*   mask = (const int*)  d_in[1];
    const float* qw = (const float*)d_in[2];
    const float* qb = (const float*)d_in[3];
    const float* kw = (const float*)d_in[4];
    const float* kb = (const float*)d_in[5];
    const float* vw = (const float*)d_in[6];
    const float* vb = (const float*)d_in[7];
    const float* ow = (const float*)d_in[8];
    const float* ob = (const float*)d_in[9];

    float* out  = (float*)d_out;                       // [4096, 768]
    float* attn = out + (size_t)Bn * Sn * Wn;          // [B,H,S,S]

    const size_t XE  = (size_t)Bn * Sn * Wn;           // 3,145,728 elems
    const size_t QKE = (size_t)Bn * Hn * Sn * Dn;      // 3,145,728 elems
    char* w = (char*)d_ws;
    unsigned short* xh   = (unsigned short*)w;  w += XE * 2;     // also aoh later
    unsigned short* xl   = (unsigned short*)w;  w += XE * 2;     // also aol later
    unsigned short* wqh  = (unsigned short*)w;  w += (size_t)3 * Wn * Wn * 2;
    unsigned short* wql  = (unsigned short*)w;  w += (size_t)3 * Wn * Wn * 2;
    unsigned short* woh  = (unsigned short*)w;  w += (size_t)Wn * Wn * 2;
    unsigned short* wol  = (unsigned short*)w;  w += (size_t)Wn * Wn * 2;
    float*          bq   = (float*)w;           w += (size_t)3 * Wn * 4;
    unsigned short* qh_w = (unsigned short*)w;  w += QKE * 2;
    unsigned short* ql_w = (unsigned short*)w;  w += QKE * 2;
    unsigned short* kh_w = (unsigned short*)w;  w += QKE * 2;
    unsigned short* kl_w = (unsigned short*)w;  w += QKE * 2;
    unsigned short* vt_w = (unsigned short*)w;  w += QKE * 2;

    split_x_kernel<<<3072, 256, 0, stream>>>(x, xh, xl);
    split_w_kernel<<<576, 256, 0, stream>>>(qw, wqh, wql);
    split_w_kernel<<<576, 256, 0, stream>>>(kw, wqh + (size_t)Wn * Wn, wql + (size_t)Wn * Wn);
    split_w_kernel<<<576, 256, 0, stream>>>(vw, wqh + (size_t)2 * Wn * Wn, wql + (size_t)2 * Wn * Wn);
    split_w_kernel<<<576, 256, 0, stream>>>(ow, woh, wol);
    concat_bias_kernel<<<9, 256, 0, stream>>>(qb, kb, vb, bq);

    qkv_mfma_kernel<<<dim3(32, 18), 256, 0, stream>>>(
        xh, xl, wqh, wql, bq, qh_w, ql_w, kh_w, kl_w, vt_w);

    attn_mfma_kernel<<<dim3(32, Hn, Bn), 128, 0, stream>>>(
        qh_w, ql_w, kh_w, kl_w, vt_w, mask, attn, xh, xl);

    oproj_mfma_kernel<<<dim3(32, 6), 256, 0, stream>>>(
        xh, xl, woh, wol, ob, out);
}

// Round 4
// 451.216 us; speedup vs baseline: 1.0809x; 1.0809x over previous
//
#include <hip/hip_runtime.h>

#define Bn 4
#define Sn 1024
#define En 1024
#define Wn 768
#define Hn 12
#define Dn 64
#define XE ((size_t)Bn * Sn * Wn)   // 3,145,728

typedef __attribute__((ext_vector_type(8))) short short8;
typedef __attribute__((ext_vector_type(4))) short short4v;
typedef __attribute__((ext_vector_type(4))) float floatx4;

#define MFMA16(A, B, C) __builtin_amdgcn_mfma_f32_16x16x32_bf16(A, B, C, 0, 0, 0)

__device__ __forceinline__ unsigned short f2bf_rn(float f) {
    unsigned int u = __float_as_uint(f);
    unsigned int r = u + 0x7fffu + ((u >> 16) & 1u);
    return (unsigned short)(r >> 16);
}
__device__ __forceinline__ float bf2f(unsigned short h) {
    return __uint_as_float(((unsigned int)h) << 16);
}

__device__ __forceinline__ void gload_lds16(const unsigned short* g, unsigned short* l) {
    __builtin_amdgcn_global_load_lds(
        (const __attribute__((address_space(1))) void*)g,
        (__attribute__((address_space(3))) void*)l, 16, 0, 0);
}

// ---------------------------------------------------------------------------
// Fused prep: x split (3072 blocks) + 3 qkv-weight splits (1728) +
// o-weight split (576) + bias concat (9).
// ---------------------------------------------------------------------------
__global__ __launch_bounds__(256) void prep_kernel(
    const float* __restrict__ x,
    const float* __restrict__ qw, const float* __restrict__ kw,
    const float* __restrict__ vw, const float* __restrict__ ow,
    const float* __restrict__ qb, const float* __restrict__ kb,
    const float* __restrict__ vb,
    unsigned short* __restrict__ xh, unsigned short* __restrict__ xl,
    unsigned short* __restrict__ wqh, unsigned short* __restrict__ wql,
    unsigned short* __restrict__ woh, unsigned short* __restrict__ wol,
    float* __restrict__ bq)
{
    const int bx = blockIdx.x;
    const float* src; unsigned short *dh, *dl; int e;
    if (bx < 3072) {
        e = (bx * 256 + threadIdx.x) * 4;
        src = x; dh = xh; dl = xl;
    } else if (bx < 3072 + 1728) {
        int bb = bx - 3072; int which = bb / 576;
        e = ((bb - which * 576) * 256 + threadIdx.x) * 4;
        src = (which == 0) ? qw : (which == 1) ? kw : vw;
        dh = wqh + (size_t)which * Wn * Wn;
        dl = wql + (size_t)which * Wn * Wn;
    } else if (bx < 3072 + 1728 + 576) {
        e = ((bx - 3072 - 1728) * 256 + threadIdx.x) * 4;
        src = ow; dh = woh; dl = wol;
    } else {
        int t = (bx - 3072 - 1728 - 576) * 256 + threadIdx.x;
        if (t < Wn) bq[t] = qb[t];
        else if (t < 2 * Wn) bq[t] = kb[t - Wn];
        else if (t < 3 * Wn) bq[t] = vb[t - 2 * Wn];
        return;
    }
    int row = e / Wn, col = e - row * Wn;
    float4 v = *(const float4*)(src + (size_t)row * En + col);
    float f[4] = {v.x, v.y, v.z, v.w};
    short4v h, l;
    #pragma unroll
    for (int i = 0; i < 4; ++i) {
        unsigned short hh = f2bf_rn(f[i]);
        h[i] = (short)hh;
        l[i] = (short)f2bf_rn(f[i] - bf2f(hh));
    }
    *(short4v*)(dh + e) = h;
    *(short4v*)(dl + e) = l;
}

// ---------------------------------------------------------------------------
// QKV GEMM (bf16x3 MFMA).  q/k out: fp32 [B,H,S,D]; v out: bf16 [B,H,D,S].
// ---------------------------------------------------------------------------
__global__ __launch_bounds__(256) void qkv_mfma_kernel(
    const unsigned short* __restrict__ xh, const unsigned short* __restrict__ xl,
    const unsigned short* __restrict__ wh, const unsigned short* __restrict__ wl,
    const float* __restrict__ bq,
    float* __restrict__ q32, float* __restrict__ k32,
    unsigned short* __restrict__ vt_o)
{
    __shared__ __align__(16) unsigned short Ah[128 * 32];
    __shared__ __align__(16) unsigned short Al[128 * 32];
    __shared__ __align__(16) unsigned short Bh[128 * 32];
    __shared__ __align__(16) unsigned short Bl[128 * 32];

    const int tid = threadIdx.x;
    const int wave = tid >> 6, lane = tid & 63;
    const int quad = lane >> 4, l16 = lane & 15;
    const int m0 = blockIdx.x * 128, n0 = blockIdx.y * 128;
    const int wm = wave >> 1, wn = wave & 1;

    floatx4 acc[4][4] = {};

    const unsigned short* gsrc = (wave == 0) ? xh : (wave == 1) ? xl
                               : (wave == 2) ? wh : wl;
    unsigned short* ldst = (wave == 0) ? Ah : (wave == 1) ? Al
                         : (wave == 2) ? Bh : Bl;
    const int base_row = (wave < 2) ? m0 : n0;
    const int r_in = lane >> 2;
    const int cs = (lane & 3) ^ (r_in & 3);

    for (int k0 = 0; k0 < Wn; k0 += 32) {
        #pragma unroll
        for (int i = 0; i < 8; ++i) {
            int r = i * 16 + r_in;
            const unsigned short* gp =
                gsrc + (size_t)(base_row + r) * Wn + k0 + cs * 8;
            gload_lds16(gp, ldst + i * 512);
        }
        __syncthreads();

        short8 afh[4], afl[4], bfh[4], bfl[4];
        #pragma unroll
        for (int t = 0; t < 4; ++t) {
            int mr = wm * 64 + t * 16 + l16;
            int ca = quad ^ (mr & 3);
            afh[t] = *(const short8*)(Ah + mr * 32 + ca * 8);
            afl[t] = *(const short8*)(Al + mr * 32 + ca * 8);
            int nr = wn * 64 + t * 16 + l16;
            int cb = quad ^ (nr & 3);
            bfh[t] = *(const short8*)(Bh + nr * 32 + cb * 8);
            bfl[t] = *(const short8*)(Bl + nr * 32 + cb * 8);
        }
        #pragma unroll
        for (int mt = 0; mt < 4; ++mt)
            #pragma unroll
            for (int nt = 0; nt < 4; ++nt) {
                acc[mt][nt] = MFMA16(afh[mt], bfh[nt], acc[mt][nt]);
                acc[mt][nt] = MFMA16(afh[mt], bfl[nt], acc[mt][nt]);
                acc[mt][nt] = MFMA16(afl[mt], bfh[nt], acc[mt][nt]);
            }
        __syncthreads();
    }

    const int which = n0 / Wn;                 // 0=q 1=k 2=v
    const int b = m0 >> 10;
    #pragma unroll
    for (int nt = 0; nt < 4; ++nt) {
        const int ng = n0 + wn * 64 + nt * 16 + l16;
        const float bias = bq[ng];
        const int f = ng - which * Wn;
        const int h = f >> 6, d = f & 63;
        #pragma unroll
        for (int mt = 0; mt < 4; ++mt) {
            const int mbase = m0 + wm * 64 + mt * 16 + quad * 4;
            const int s0 = mbase & (Sn - 1);
            if (which < 2) {
                float* o32 = which ? k32 : q32;
                size_t idx = (((size_t)(b * Hn + h)) * Sn + s0) * Dn + d;
                #pragma unroll
                for (int r = 0; r < 4; ++r)
                    o32[idx + (size_t)r * Dn] = acc[mt][nt][r] + bias;
            } else {
                size_t idx = (((size_t)(b * Hn + h)) * Dn + d) * Sn + s0;
                short4v pk;
                #pragma unroll
                for (int r = 0; r < 4; ++r)
                    pk[r] = (short)f2bf_rn(acc[mt][nt][r] + bias);
                *(short4v*)(vt_o + idx) = pk;
            }
        }
    }
}

// ---------------------------------------------------------------------------
// Attention pass A: partial softmax denominators over a 256-key range.
// grid.x = qt*4 + ks (64), y=h, z=b -> 3072 blocks.
// ---------------------------------------------------------------------------
__global__ __launch_bounds__(256) void attn_sum_kernel(
    const float* __restrict__ q32, const float* __restrict__ k32,
    const int* __restrict__ mask, float* __restrict__ lpart)
{
    __shared__ __align__(16) unsigned short Kh[64 * 72];
    __shared__ __align__(16) unsigned short Kl[64 * 72];
    __shared__ float msk[64];

    const int tid = threadIdx.x;
    const int wave = tid >> 6, lane = tid & 63;
    const int quad = lane >> 4, l16 = lane & 15;
    const int qt = blockIdx.x >> 2, ks = blockIdx.x & 3;
    const int h = blockIdx.y, b = blockIdx.z;
    const int bh = b * Hn + h;
    const size_t kvb = (size_t)bh * Sn * Dn;

    short8 qfh[2], qfl[2];
    {
        const int s = qt * 64 + wave * 16 + l16;
        const float* qp = q32 + kvb + (size_t)s * Dn + quad * 8;
        #pragma unroll
        for (int ksp = 0; ksp < 2; ++ksp) {
            float f[8];
            *(float4*)&f[0] = *(const float4*)(qp + ksp * 32);
            *(float4*)&f[4] = *(const float4*)(qp + ksp * 32 + 4);
            #pragma unroll
            for (int j = 0; j < 8; ++j) {
                unsigned short hh = f2bf_rn(f[j]);
                qfh[ksp][j] = (short)hh;
                qfl[ksp][j] = (short)f2bf_rn(f[j] - bf2f(hh));
            }
        }
    }

    const int sr = tid >> 2, sc = tid & 3;
    float lsum[4] = {0.f, 0.f, 0.f, 0.f};

    for (int kt = 0; kt < 4; ++kt) {
        __syncthreads();
        {
            const float* kp = k32 + kvb + (size_t)(ks * 256 + kt * 64 + sr) * Dn + sc * 16;
            float f[16];
            *(float4*)&f[0]  = *(const float4*)(kp);
            *(float4*)&f[4]  = *(const float4*)(kp + 4);
            *(float4*)&f[8]  = *(const float4*)(kp + 8);
            *(float4*)&f[12] = *(const float4*)(kp + 12);
            short8 h0, h1, l0, l1;
            #pragma unroll
            for (int j = 0; j < 8; ++j) {
                unsigned short hh = f2bf_rn(f[j]);
                h0[j] = (short)hh; l0[j] = (short)f2bf_rn(f[j] - bf2f(hh));
                unsigned short hh2 = f2bf_rn(f[8 + j]);
                h1[j] = (short)hh2; l1[j] = (short)f2bf_rn(f[8 + j] - bf2f(hh2));
            }
            *(short8*)&Kh[sr * 72 + sc * 16]     = h0;
            *(short8*)&Kh[sr * 72 + sc * 16 + 8] = h1;
            *(short8*)&Kl[sr * 72 + sc * 16]     = l0;
            *(short8*)&Kl[sr * 72 + sc * 16 + 8] = l1;
            if (tid < 64) msk[tid] = (float)mask[b * Sn + ks * 256 + kt * 64 + tid];
        }
        __syncthreads();
        #pragma unroll
        for (int ct = 0; ct < 4; ++ct) {
            floatx4 acc = {0.f, 0.f, 0.f, 0.f};
            const int key = ct * 16 + l16;
            #pragma unroll
            for (int ksp = 0; ksp < 2; ++ksp) {
                short8 b8h = *(const short8*)&Kh[key * 72 + ksp * 32 + quad * 8];
                short8 b8l = *(const short8*)&Kl[key * 72 + ksp * 32 + quad * 8];
                acc = MFMA16(qfh[ksp], b8h, acc);
                acc = MFMA16(qfh[ksp], b8l, acc);
                acc = MFMA16(qfl[ksp], b8h, acc);
            }
            const float mv = msk[key];
            #pragma unroll
            for (int r = 0; r < 4; ++r)
                lsum[r] += __expf(acc[r] * 0.125f) * mv;
        }
    }

    #pragma unroll
    for (int r = 0; r < 4; ++r) {
        float v = lsum[r];
        v += __shfl_xor(v, 1, 64);
        v += __shfl_xor(v, 2, 64);
        v += __shfl_xor(v, 4, 64);
        v += __shfl_xor(v, 8, 64);
        lsum[r] = v;
    }
    if (l16 == 0) {
        const int row = qt * 64 + wave * 16 + quad * 4;
        #pragma unroll
        for (int r = 0; r < 4; ++r)
            lpart[((size_t)ks * Bn * Hn + bh) * Sn + row + r] = lsum[r];
    }
}

// ---------------------------------------------------------------------------
// Attention pass B: recompute scores on the key range, write fp32 weights,
// accumulate partial O into per-ksplit slab.
// ---------------------------------------------------------------------------
__global__ __launch_bounds__(256) void attn_out_kernel(
    const float* __restrict__ q32, const float* __restrict__ k32,
    const unsigned short* __restrict__ vt, const int* __restrict__ mask,
    const float* __restrict__ lpart, float* __restrict__ attn,
    float* __restrict__ opart)
{
    __shared__ __align__(16) unsigned short Kh[64 * 72];
    __shared__ __align__(16) unsigned short Kl[64 * 72];
    __shared__ __align__(16) unsigned short Vs[64 * 72];
    __shared__ __align__(16) unsigned short Ps[4][16 * 72];
    __shared__ float msk[64];

    const int tid = threadIdx.x;
    const int wave = tid >> 6, lane = tid & 63;
    const int quad = lane >> 4, l16 = lane & 15;
    const int qt = blockIdx.x >> 2, ks = blockIdx.x & 3;
    const int h = blockIdx.y, b = blockIdx.z;
    const int bh = b * Hn + h;
    const size_t kvb = (size_t)bh * Sn * Dn;

    short8 qfh[2], qfl[2];
    {
        const int s = qt * 64 + wave * 16 + l16;
        const float* qp = q32 + kvb + (size_t)s * Dn + quad * 8;
        #pragma unroll
        for (int ksp = 0; ksp < 2; ++ksp) {
            float f[8];
            *(float4*)&f[0] = *(const float4*)(qp + ksp * 32);
            *(float4*)&f[4] = *(const float4*)(qp + ksp * 32 + 4);
            #pragma unroll
            for (int j = 0; j < 8; ++j) {
                unsigned short hh = f2bf_rn(f[j]);
                qfh[ksp][j] = (short)hh;
                qfl[ksp][j] = (short)f2bf_rn(f[j] - bf2f(hh));
            }
        }
    }

    float li[4];
    {
        const int row = qt * 64 + wave * 16 + quad * 4;
        #pragma unroll
        for (int r = 0; r < 4; ++r) {
            float lv = 0.f;
            #pragma unroll
            for (int s4 = 0; s4 < 4; ++s4)
                lv += lpart[((size_t)s4 * Bn * Hn + bh) * Sn + row + r];
            li[r] = (lv > 0.f) ? 1.f / lv : 0.f;
        }
    }

    const int sr = tid >> 2, sc = tid & 3;
    const size_t vbase = (size_t)bh * Dn * Sn;
    floatx4 oacc[4] = {};

    for (int kt = 0; kt < 4; ++kt) {
        __syncthreads();
        {
            const float* kp = k32 + kvb + (size_t)(ks * 256 + kt * 64 + sr) * Dn + sc * 16;
            float f[16];
            *(float4*)&f[0]  = *(const float4*)(kp);
            *(float4*)&f[4]  = *(const float4*)(kp + 4);
            *(float4*)&f[8]  = *(const float4*)(kp + 8);
            *(float4*)&f[12] = *(const float4*)(kp + 12);
            short8 h0, h1, l0, l1;
            #pragma unroll
            for (int j = 0; j < 8; ++j) {
                unsigned short hh = f2bf_rn(f[j]);
                h0[j] = (short)hh; l0[j] = (short)f2bf_rn(f[j] - bf2f(hh));
                unsigned short hh2 = f2bf_rn(f[8 + j]);
                h1[j] = (short)hh2; l1[j] = (short)f2bf_rn(f[8 + j] - bf2f(hh2));
            }
            *(short8*)&Kh[sr * 72 + sc * 16]     = h0;
            *(short8*)&Kh[sr * 72 + sc * 16 + 8] = h1;
            *(short8*)&Kl[sr * 72 + sc * 16]     = l0;
            *(short8*)&Kl[sr * 72 + sc * 16 + 8] = l1;
            const size_t g2 = vbase + (size_t)sr * Sn + ks * 256 + kt * 64 + sc * 16;
            *(short8*)&Vs[sr * 72 + sc * 16]     = *(const short8*)(vt + g2);
            *(short8*)&Vs[sr * 72 + sc * 16 + 8] = *(const short8*)(vt + g2 + 8);
            if (tid < 64) msk[tid] = (float)mask[b * Sn + ks * 256 + kt * 64 + tid];
        }
        __syncthreads();

        #pragma unroll
        for (int ct = 0; ct < 4; ++ct) {
            floatx4 acc = {0.f, 0.f, 0.f, 0.f};
            const int key = ct * 16 + l16;
            #pragma unroll
            for (int ksp = 0; ksp < 2; ++ksp) {
                short8 b8h = *(const short8*)&Kh[key * 72 + ksp * 32 + quad * 8];
                short8 b8l = *(const short8*)&Kl[key * 72 + ksp * 32 + quad * 8];
                acc = MFMA16(qfh[ksp], b8h, acc);
                acc = MFMA16(qfh[ksp], b8l, acc);
                acc = MFMA16(qfl[ksp], b8h, acc);
            }
            const float mv = msk[key];
            const int row0 = qt * 64 + wave * 16 + quad * 4;
            const int key_g = ks * 256 + kt * 64 + key;
            #pragma unroll
            for (int r = 0; r < 4; ++r) {
                float p = __expf(acc[r] * 0.125f) * mv * li[r];
                attn[((size_t)bh * Sn + row0 + r) * Sn + key_g] = p;
                Ps[wave][(quad * 4 + r) * 72 + key] = f2bf_rn(p);
            }
        }
        // PV: wave-local Ps (in-wave LDS ordering; compiler inserts lgkmcnt)
        #pragma unroll
        for (int ksp = 0; ksp < 2; ++ksp) {
            short8 pf = *(const short8*)&Ps[wave][l16 * 72 + ksp * 32 + quad * 8];
            #pragma unroll
            for (int dt = 0; dt < 4; ++dt) {
                short8 vf = *(const short8*)&Vs[(dt * 16 + l16) * 72 + ksp * 32 + quad * 8];
                oacc[dt] = MFMA16(pf, vf, oacc[dt]);
            }
        }
    }

    const int s0 = qt * 64 + wave * 16 + quad * 4;
    #pragma unroll
    for (int dt = 0; dt < 4; ++dt)
        #pragma unroll
        for (int r = 0; r < 4; ++r)
            opart[(size_t)ks * XE + ((size_t)b * Sn + s0 + r) * Wn
                  + h * Dn + dt * 16 + l16] = oacc[dt][r];
}

// ---------------------------------------------------------------------------
// Reduce 4 partial-O slabs -> bf16 hi/lo AO [B,S,W].
// ---------------------------------------------------------------------------
__global__ __launch_bounds__(256) void reduce_ao_kernel(
    const float* __restrict__ opart, unsigned short* __restrict__ aoh,
    unsigned short* __restrict__ aol)
{
    size_t e = ((size_t)blockIdx.x * 256 + threadIdx.x) * 4;
    float4 a0 = *(const float4*)(opart + e);
    float4 a1 = *(const float4*)(opart + XE + e);
    float4 a2 = *(const float4*)(opart + 2 * XE + e);
    float4 a3 = *(const float4*)(opart + 3 * XE + e);
    float f[4] = {a0.x + a1.x + a2.x + a3.x, a0.y + a1.y + a2.y + a3.y,
                  a0.z + a1.z + a2.z + a3.z, a0.w + a1.w + a2.w + a3.w};
    short4v h, l;
    #pragma unroll
    for (int i = 0; i < 4; ++i) {
        unsigned short hh = f2bf_rn(f[i]);
        h[i] = (short)hh;
        l[i] = (short)f2bf_rn(f[i] - bf2f(hh));
    }
    *(short4v*)(aoh + e) = h;
    *(short4v*)(aol + e) = l;
}

// ---------------------------------------------------------------------------
// O projection: 64x128 tiles -> grid (64,6) = 384 blocks.
// ---------------------------------------------------------------------------
__global__ __launch_bounds__(256) void oproj_mfma_kernel(
    const unsigned short* __restrict__ aoh, const unsigned short* __restrict__ aol,
    const unsigned short* __restrict__ wh, const unsigned short* __restrict__ wl,
    const float* __restrict__ ob, float* __restrict__ out)
{
    __shared__ __align__(16) unsigned short Ah[64 * 32];
    __shared__ __align__(16) unsigned short Al[64 * 32];
    __shared__ __align__(16) unsigned short Bh[128 * 32];
    __shared__ __align__(16) unsigned short Bl[128 * 32];

    const int tid = threadIdx.x;
    const int wave = tid >> 6, lane = tid & 63;
    const int quad = lane >> 4, l16 = lane & 15;
    const int m0 = blockIdx.x * 64, n0 = blockIdx.y * 128;
    const int wm = wave >> 1, wn = wave & 1;

    floatx4 acc[2][4] = {};

    const int r_in = lane >> 2;
    const int cs = (lane & 3) ^ (r_in & 3);

    for (int k0 = 0; k0 < Wn; k0 += 32) {
        if (wave == 0) {
            #pragma unroll
            for (int i = 0; i < 4; ++i) {
                gload_lds16(aoh + (size_t)(m0 + i * 16 + r_in) * Wn + k0 + cs * 8,
                            Ah + i * 512);
                gload_lds16(aol + (size_t)(m0 + i * 16 + r_in) * Wn + k0 + cs * 8,
                            Al + i * 512);
            }
        } else if (wave == 1) {
            #pragma unroll
            for (int i = 0; i < 8; ++i)
                gload_lds16(wh + (size_t)(n0 + i * 16 + r_in) * Wn + k0 + cs * 8,
                            Bh + i * 512);
        } else if (wave == 2) {
            #pragma unroll
            for (int i = 0; i < 8; ++i)
                gload_lds16(wl + (size_t)(n0 + i * 16 + r_in) * Wn + k0 + cs * 8,
                            Bl + i * 512);
        }
        __syncthreads();

        short8 afh[2], afl[2], bfh[4], bfl[4];
        #pragma unroll
        for (int t = 0; t < 2; ++t) {
            int mr = wm * 32 + t * 16 + l16;
            int ca = quad ^ (mr & 3);
            afh[t] = *(const short8*)(Ah + mr * 32 + ca * 8);
            afl[t] = *(const short8*)(Al + mr * 32 + ca * 8);
        }
        #pragma unroll
        for (int t = 0; t < 4; ++t) {
            int nr = wn * 64 + t * 16 + l16;
            int cb = quad ^ (nr & 3);
            bfh[t] = *(const short8*)(Bh + nr * 32 + cb * 8);
            bfl[t] = *(const short8*)(Bl + nr * 32 + cb * 8);
        }
        #pragma unroll
        for (int mt = 0; mt < 2; ++mt)
            #pragma unroll
            for (int nt = 0; nt < 4; ++nt) {
                acc[mt][nt] = MFMA16(afh[mt], bfh[nt], acc[mt][nt]);
                acc[mt][nt] = MFMA16(afh[mt], bfl[nt], acc[mt][nt]);
                acc[mt][nt] = MFMA16(afl[mt], bfh[nt], acc[mt][nt]);
            }
        __syncthreads();
    }

    #pragma unroll
    for (int nt = 0; nt < 4; ++nt) {
        const int ng = n0 + wn * 64 + nt * 16 + l16;
        const float bias = ob[ng];
        #pragma unroll
        for (int mt = 0; mt < 2; ++mt) {
            const int m = m0 + wm * 32 + mt * 16 + quad * 4;
            #pragma unroll
            for (int r = 0; r < 4; ++r)
                out[(size_t)(m + r) * Wn + ng] = acc[mt][nt][r] + bias;
        }
    }
}

// ---------------------------------------------------------------------------
extern "C" void kernel_launch(void* const* d_in, const int* in_sizes, int n_in,
                              void* d_out, int out_size, void* d_ws, size_t ws_size,
                              hipStream_t stream) {
    const float* x    = (const float*)d_in[0];
    const int*   mask = (const int*)  d_in[1];
    const float* qw = (const float*)d_in[2];
    const float* qb = (const float*)d_in[3];
    const float* kw = (const float*)d_in[4];
    const float* kb = (const float*)d_in[5];
    const float* vw = (const float*)d_in[6];
    const float* vb = (const float*)d_in[7];
    const float* ow = (const float*)d_in[8];
    const float* ob = (const float*)d_in[9];

    float* out  = (float*)d_out;                       // [4096, 768]
    float* attn = out + XE;                            // [B,H,S,S]

    char* w = (char*)d_ws;
    unsigned short* xh   = (unsigned short*)w;  w += XE * 2;     // also aoh
    unsigned short* xl   = (unsigned short*)w;  w += XE * 2;     // also aol
    unsigned short* wqh  = (unsigned short*)w;  w += (size_t)3 * Wn * Wn * 2;
    unsigned short* wql  = (unsigned short*)w;  w += (size_t)3 * Wn * Wn * 2;
    unsigned short* woh  = (unsigned short*)w;  w += (size_t)Wn * Wn * 2;
    unsigned short* wol  = (unsigned short*)w;  w += (size_t)Wn * Wn * 2;
    float*          bq   = (float*)w;           w += (size_t)3 * Wn * 4;
    float*          q32  = (float*)w;           w += XE * 4;
    float*          k32  = (float*)w;           w += XE * 4;
    unsigned short* vt_w = (unsigned short*)w;  w += XE * 2;
    float*          lpart = (float*)w;          w += (size_t)4 * Bn * Hn * Sn * 4;
    float*          opart = (float*)w;          w += (size_t)4 * XE * 4;

    prep_kernel<<<5385, 256, 0, stream>>>(x, qw, kw, vw, ow, qb, kb, vb,
                                          xh, xl, wqh, wql, woh, wol, bq);

    qkv_mfma_kernel<<<dim3(32, 18), 256, 0, stream>>>(
        xh, xl, wqh, wql, bq, q32, k32, vt_w);

    attn_sum_kernel<<<dim3(64, Hn, Bn), 256, 0, stream>>>(
        q32, k32, mask, lpart);

    attn_out_kernel<<<dim3(64, Hn, Bn), 256, 0, stream>>>(
        q32, k32, vt_w, mask, lpart, attn, opart);

    reduce_ao_kernel<<<3072, 256, 0, stream>>>(opart, xh, xl);

    oproj_mfma_kernel<<<dim3(64, 6), 256, 0, stream>>>(
        xh, xl, woh, wol, ob, out);
}